// Round 8
// baseline (1389.439 us; speedup 1.0000x reference)
//
#include <hip/hip_runtime.h>

#define N_NODES  100000
#define N_EDGES  1600000
#define NODE_DIM 64
#define EDGE_DIM 16
#define HIDDEN   64
#define AGG_BLOCKS 1280          // 5 blocks/CU * 256 CUs
#define NB1 ((N_NODES + 255) / 256)   // 391 scan blocks

typedef __bf16 bf16x8 __attribute__((ext_vector_type(8)));
typedef unsigned short u16x8 __attribute__((ext_vector_type(8)));
typedef unsigned short u16x4 __attribute__((ext_vector_type(4)));
typedef unsigned int   u32x4 __attribute__((ext_vector_type(4)));
typedef float f32x4 __attribute__((ext_vector_type(4)));

__device__ __forceinline__ unsigned short f2bf(float f) {
    unsigned int u = __float_as_uint(f);
    u += 0x7FFFu + ((u >> 16) & 1u);          // RNE
    return (unsigned short)(u >> 16);
}

__device__ __forceinline__ float bf2f(unsigned short s) {
    return __uint_as_float((unsigned int)s << 16);
}

__device__ __forceinline__ bf16x8 lds_frag(const unsigned short* p) {
    return __builtin_bit_cast(bf16x8, *(const u16x8*)p);
}

__device__ __forceinline__ unsigned pk2(float lo, float hi) {
    return ((unsigned)f2bf(hi) << 16) | (unsigned)f2bf(lo);
}

__device__ __forceinline__ void cvt4v(unsigned short* dst, float4 f) {
    u16x4 p;
    p[0]=f2bf(f.x); p[1]=f2bf(f.y); p[2]=f2bf(f.z); p[3]=f2bf(f.w);
    *(u16x4*)dst = p;
}

// ---- prep: bf16 weights (b1 folded into W1t row k=144) + bf16 x + dst degree ----
__global__ void prep_kernel(const float* __restrict__ W1, const float* __restrict__ b1,
                            const float* __restrict__ W2, const float* __restrict__ Wu,
                            const float* __restrict__ x, const int* __restrict__ ei,
                            unsigned short* __restrict__ W1t,   // [64][160]
                            unsigned short* __restrict__ W2t,   // [64][64]
                            unsigned short* __restrict__ Wut,   // [64][128]
                            unsigned short* __restrict__ xb,    // [N][64] bf16
                            int* __restrict__ deg)              // [N] (pre-zeroed)
{
    int t = blockIdx.x * 256 + threadIdx.x;
    int stride = gridDim.x * 256;
    for (int i = t; i < N_NODES * 64 / 4; i += stride) {
        float4 f = ((const float4*)x)[i];
        cvt4v(&xb[i * 4], f);
    }
    for (int e = t; e < N_EDGES; e += stride)
        atomicAdd(&deg[ei[N_EDGES + e]], 1);
    for (int i = t; i < 64 * 160; i += stride) {
        int n = i / 160, k = i % 160;
        float v = (k < 144) ? W1[k * 64 + n] : (k == 144 ? b1[n] : 0.0f);
        W1t[i] = f2bf(v);
    }
    for (int i = t; i < 64 * 64; i += stride) {
        int n = i / 64, k = i % 64;
        W2t[i] = f2bf(W2[k * 64 + n]);
    }
    for (int i = t; i < 64 * 128; i += stride) {
        int n = i / 128, k = i % 128;
        Wut[i] = f2bf(Wu[k * 64 + n]);
    }
}

// ---- CSR build: block scan -> block-sum scan -> add base, then fill edge list ----
__global__ void scan1_kernel(const int* __restrict__ deg, int* __restrict__ ofs,
                             int* __restrict__ bsum) {
    __shared__ int sh[256];
    int t = threadIdx.x, i = blockIdx.x * 256 + t;
    int v = (i < N_NODES) ? deg[i] : 0;
    sh[t] = v; __syncthreads();
    #pragma unroll
    for (int o = 1; o < 256; o <<= 1) {
        int add = (t >= o) ? sh[t - o] : 0;
        __syncthreads();
        sh[t] += add;
        __syncthreads();
    }
    if (i < N_NODES) ofs[i] = sh[t] - v;       // block-local exclusive
    if (t == 255) bsum[blockIdx.x] = sh[t];    // block total
}

__global__ void scan2_kernel(int* __restrict__ bsum) {
    __shared__ int sh[512];
    int t = threadIdx.x;
    int v = (t < NB1) ? bsum[t] : 0;
    sh[t] = v; __syncthreads();
    #pragma unroll
    for (int o = 1; o < 512; o <<= 1) {
        int add = (t >= o) ? sh[t - o] : 0;
        __syncthreads();
        sh[t] += add;
        __syncthreads();
    }
    if (t < NB1) bsum[t] = sh[t] - v;          // exclusive block bases
}

__global__ void scan3_kernel(int* __restrict__ ofs, const int* __restrict__ bsum,
                             int* __restrict__ cur) {
    int t = threadIdx.x, i = blockIdx.x * 256 + t;
    if (i < N_NODES) {
        int o = ofs[i] + bsum[blockIdx.x];
        ofs[i] = o;
        cur[i] = o;
    }
    if (blockIdx.x == 0 && t == 0) {           // tails so (ofs[n], ofs[n+1]) valid
        ofs[N_NODES]     = N_EDGES;
        ofs[N_NODES + 1] = N_EDGES;
    }
}

__global__ void fill_kernel(const int* __restrict__ ei, int* __restrict__ cur,
                            long long* __restrict__ elist) {
    int idx = blockIdx.x * 256 + threadIdx.x;
    int stride = gridDim.x * 256;
    if (idx < 16) elist[N_EDGES + idx] = 0;    // zero pad: unconditional group loads
    for (int e = idx; e < N_EDGES; e += stride) {
        int s = ei[e];
        int d = ei[N_EDGES + e];
        int pos = atomicAdd(&cur[d], 1);
        elist[pos] = ((long long)e << 32) | (unsigned int)s;  // hi: edge id, lo: src
    }
}

// LDS strides (elems)
#define SW1 164
#define SW2 66

#define MFMA_BF16 __builtin_amdgcn_mfma_f32_16x16x32_bf16
#define BC(v) __builtin_bit_cast(bf16x8, v)

// ---- gather agg: CSR, register GEMM pipeline, in-register reduce, zero atomics ----
__global__ __launch_bounds__(256, 5) void agg_kernel(
    const unsigned short* __restrict__ xb,
    const float* __restrict__ ea,
    const long long* __restrict__ elist,     // [E+16], pad zeroed
    const int* __restrict__ ofs,             // [N+2], tails = E
    const unsigned short* __restrict__ W1t,
    const unsigned short* __restrict__ W2t,
    const float* __restrict__ b2,
    unsigned short* __restrict__ agg)        // [N][64] bf16 (pre-zeroed)
{
    __shared__ __align__(16) unsigned short sW1[64 * SW1];   // 20992 B
    __shared__ __align__(16) unsigned short sW2[64 * SW2];   //  8448 B

    const int t    = threadIdx.x;
    const int lane = t & 63;
    const int w    = t >> 6;

    // ---- stage W1 with sigma column-permutation (verified r7) ----
    #pragma unroll
    for (int i = 0; i < 5; i++) {
        int c = t + i * 256;
        int row16 = c / 20, chunk = c % 20;
        int ct = row16 >> 4, ii = row16 & 15;
        int srcRow = ((ii >> 2) << 3) + (ct & 1) * 32 + ((ct >> 1) << 2) + (ii & 3);
        *(u16x8*)&sW1[row16 * SW1 + chunk * 8] = *(const u16x8*)&W1t[srcRow * 160 + chunk * 8];
    }
    #pragma unroll
    for (int i = 0; i < 2; i++) {
        int c = t + i * 256;
        int n = c >> 3, k8 = c & 7;
        *(u16x8*)&sW2[n * SW2 + k8 * 8] = *(const u16x8*)&W2t[n * 64 + k8 * 8];
    }
    __syncthreads();                         // only block-wide barrier

    const int col = lane & 15;
    const int kq  = lane >> 4;

    u16x8 padf = {0,0,0,0,0,0,0,0};
    if (kq == 2) padf[0] = 0x3F80;           // bf16 1.0 (b1 row k=144)

    // b2 for the store layout: lane (col<4, kq) writes c2 = col*16 + kq*4 + r
    float b2s[4];
    #pragma unroll
    for (int r = 0; r < 4; r++) b2s[r] = b2[(col & 3) * 16 + kq * 4 + r];

    const int TW = AGG_BLOCKS * 4;

    // ---- node A meta ----
    int nodeA = blockIdx.x * 4 + w;          // < 5120 < N
    int baseA = ofs[nodeA];
    int dgA   = ofs[nodeA + 1] - baseA;
    while (dgA == 0 && nodeA < N_NODES) {    // ~never; agg pre-zeroed
        nodeA += TW;
        if (nodeA < N_NODES) { baseA = ofs[nodeA]; dgA = ofs[nodeA + 1] - baseA; }
    }
    if (nodeA >= N_NODES) return;

    // ---- node B meta + node C ofs pair (pipeline) ----
    int nodeB = nodeA + TW;
    int baseB, dgB;
    {
        int ix = nodeB < N_NODES ? nodeB : N_NODES;
        baseB = ofs[ix]; dgB = ofs[ix + 1] - baseB;
        while (dgB == 0 && nodeB < N_NODES) {
            nodeB += TW;
            int ix2 = nodeB < N_NODES ? nodeB : N_NODES;
            baseB = ofs[ix2]; dgB = ofs[ix2 + 1] - baseB;
        }
    }
    int nodeC = nodeB + TW;
    int pC0, pC1;
    {
        int ix = nodeC < N_NODES ? nodeC : N_NODES;
        pC0 = ofs[ix]; pC1 = ofs[ix + 1];
    }

    // ---- dst rows, register-resident per node: A current, B prefetched ----
    const u16x8* pdA = (const u16x8*)(xb + (size_t)nodeA * 64);
    u16x8 dfA0 = pdA[kq], dfA1 = pdA[4 + kq];
    int nbsB = nodeB < N_NODES ? nodeB : 0;
    const u16x8* pdB = (const u16x8*)(xb + (size_t)nbsB * 64);
    u16x8 dfB0 = pdB[kq], dfB1 = pdB[4 + kq];

    // ---- first gather: group 0 of node A; lane's edge = col ----
    long long se = elist[baseA + col];
    {
    }
    int srcI = (int)(se & 0xffffffffLL), eid = (int)(se >> 32);
    const u16x8* ps = (const u16x8*)(xb + (size_t)srcI * 64);
    u16x8 sf0 = ps[kq], sf1 = ps[4 + kq];
    float4 ea0 = {0,0,0,0}, ea1 = {0,0,0,0};
    if (kq < 2) {
        const float4* pe = (const float4*)(ea + (size_t)eid * 16 + kq * 8);
        ea0 = pe[0]; ea1 = pe[1];
    }

    int g0 = 0;
    float aggv[16];
    #pragma unroll
    for (int i = 0; i < 16; i++) aggv[i] = 0.0f;

    for (;;) {
        const int remv = dgA - g0;
        const int rem  = remv < 16 ? remv : 16;
        const bool last = (g0 + 16 >= dgA);

        // ---- prefetch next work item's elist row ----
        const int nb = last ? baseB : (baseA + g0 + 16);
        long long seN = elist[nb + col];     // padded: unconditional, safe at E

        // ---- current ea fragment (bf16) ----
        u16x8 ef;
        ef[0]=f2bf(ea0.x); ef[1]=f2bf(ea0.y); ef[2]=f2bf(ea0.z); ef[3]=f2bf(ea0.w);
        ef[4]=f2bf(ea1.x); ef[5]=f2bf(ea1.y); ef[6]=f2bf(ea1.z); ef[7]=f2bf(ea1.w);
        u16x8 b4u = (kq < 2) ? ef : padf;

        // ---- GEMM1-T: H^T = W1^T(perm) @ Ain^T (b1 via k=144) ----
        f32x4 a[4] = {{0,0,0,0},{0,0,0,0},{0,0,0,0},{0,0,0,0}};
        #define G1STEP(KS, BB)                                                          \
        {   int ko = (KS) * 32 + kq * 8;                                                \
            a[0] = MFMA_BF16(lds_frag(&sW1[( 0 + col) * SW1 + ko]), BC(BB), a[0],0,0,0);\
            a[1] = MFMA_BF16(lds_frag(&sW1[(16 + col) * SW1 + ko]), BC(BB), a[1],0,0,0);\
            a[2] = MFMA_BF16(lds_frag(&sW1[(32 + col) * SW1 + ko]), BC(BB), a[2],0,0,0);\
            a[3] = MFMA_BF16(lds_frag(&sW1[(48 + col) * SW1 + ko]), BC(BB), a[3],0,0,0);\
        }
        G1STEP(0, sf0)
        G1STEP(1, sf1)
        G1STEP(2, dfA0)
        G1STEP(3, dfA1)
        G1STEP(4, b4u)
        #undef G1STEP

        // ---- issue NEXT gathers (cover GEMM2 + reduction) ----
        int srcN = (int)(seN & 0xffffffffLL), eidN = (int)(seN >> 32);
        const u16x8* psN = (const u16x8*)(xb + (size_t)srcN * 64);
        u16x8 sfN0 = psN[kq], sfN1 = psN[4 + kq];
        float4 eaN0 = {0,0,0,0}, eaN1 = {0,0,0,0};
        if (kq < 2) {
            const float4* pe = (const float4*)(ea + (size_t)eidN * 16 + kq * 8);
            eaN0 = pe[0]; eaN1 = pe[1];
        }

        // ---- relu + pack -> GEMM2 B-fragments (sigma layout, verified r7) ----
        unsigned p0 = pk2(fmaxf(a[0][0],0.f), fmaxf(a[0][1],0.f));
        unsigned p1 = pk2(fmaxf(a[0][2],0.f), fmaxf(a[0][3],0.f));
        unsigned p2 = pk2(fmaxf(a[1][0],0.f), fmaxf(a[1][1],0.f));
        unsigned p3 = pk2(fmaxf(a[1][2],0.f), fmaxf(a[1][3],0.f));
        unsigned p4 = pk2(fmaxf(a[2][0],0.f), fmaxf(a[2][1],0.f));
        unsigned p5 = pk2(fmaxf(a[2][2],0.f), fmaxf(a[2][3],0.f));
        unsigned p6 = pk2(fmaxf(a[3][0],0.f), fmaxf(a[3][1],0.f));
        unsigned p7 = pk2(fmaxf(a[3][2],0.f), fmaxf(a[3][3],0.f));
        u32x4 h0v = {p0, p1, p4, p5};
        u32x4 h1v = {p2, p3, p6, p7};
        bf16x8 hf0 = __builtin_bit_cast(bf16x8, h0v);
        bf16x8 hf1 = __builtin_bit_cast(bf16x8, h1v);

        // ---- GEMM2-T: M^T = W2^T @ H^T (b2 deferred to store) ----
        f32x4 m[4] = {{0,0,0,0},{0,0,0,0},{0,0,0,0},{0,0,0,0}};
        {
            int ko = kq * 8;
            #pragma unroll
            for (int ct = 0; ct < 4; ct++)
                m[ct] = MFMA_BF16(lds_frag(&sW2[(ct * 16 + col) * SW2 + ko]), hf0, m[ct],0,0,0);
            ko += 32;
            #pragma unroll
            for (int ct = 0; ct < 4; ct++)
                m[ct] = MFMA_BF16(lds_frag(&sW2[(ct * 16 + col) * SW2 + ko]), hf1, m[ct],0,0,0);
        }

        // ---- mask pad edges + butterfly reduce across the 16 edge-lanes ----
        const float msk = (col < rem) ? 1.0f : 0.0f;
        #pragma unroll
        for (int ct = 0; ct < 4; ct++) {
            #pragma unroll
            for (int r = 0; r < 4; r++) {
                float v = m[ct][r] * msk;
                v += __shfl_xor(v, 1);
                v += __shfl_xor(v, 2);
                v += __shfl_xor(v, 4);
                v += __shfl_xor(v, 8);
                aggv[ct * 4 + r] += v;       // all 16 col-lanes now identical
            }
        }

        if (last) {
            // ---- store node row: mean + b2; lanes col<4 cover 128B coalesced ----
            const float inv = 1.0f / ((float)dgA + 1e-6f);
            if (col < 4) {
                u16x4 o;
                #pragma unroll
                for (int cc = 0; cc < 4; cc++) {
                    if (col == cc) {
                        #pragma unroll
                        for (int r = 0; r < 4; r++)
                            o[r] = f2bf(aggv[cc * 4 + r] * inv + b2s[r]);
                    }
                }
                *(u16x4*)&agg[(size_t)nodeA * 64 + col * 16 + kq * 4] = o;
            }
            if (nodeB >= N_NODES) break;
            #pragma unroll
            for (int i = 0; i < 16; i++) aggv[i] = 0.0f;

            // shift pipeline: A <- B, B <- C
            nodeA = nodeB; baseA = baseB; dgA = dgB; g0 = 0;
            dfA0 = dfB0; dfA1 = dfB1;
            nodeB = nodeC; baseB = pC0; dgB = pC1 - pC0;
            while (dgB == 0 && nodeB < N_NODES) {          // ~never
                nodeB += TW;
                int ix = nodeB < N_NODES ? nodeB : N_NODES;
                baseB = ofs[ix]; dgB = ofs[ix + 1] - baseB;
            }
            nodeC = nodeB + TW;
            {
                int ix = nodeC < N_NODES ? nodeC : N_NODES;
                pC0 = ofs[ix]; pC1 = ofs[ix + 1];
            }
            int nbs2 = nodeB < N_NODES ? nodeB : 0;
            const u16x8* pdB2 = (const u16x8*)(xb + (size_t)nbs2 * 64);
            dfB0 = pdB2[kq]; dfB1 = pdB2[4 + kq];
        } else {
            g0 += 16;
        }

        // rotate prefetched gather into current
        sf0 = sfN0; sf1 = sfN1; ea0 = eaN0; ea1 = eaN1;
    }
}

// ---- node update: A-operand direct from xb/agg (both bf16), Wu from LDS ----
#define NSA 136
__global__ __launch_bounds__(256, 6) void node_kernel(
    const float* __restrict__ x,
    const unsigned short* __restrict__ xb,    // [N][64] bf16
    const unsigned short* __restrict__ agg,   // [N][64] bf16 (mean + b2 included)
    const unsigned short* __restrict__ Wut,
    const float* __restrict__ bu,
    float* __restrict__ out)
{
    __shared__ __align__(16) unsigned short sWu[64 * NSA];   // 17408 B
    const int t = threadIdx.x, lane = t & 63, w = t >> 6;
    const int n0 = blockIdx.x * 64;
    const int col = lane & 15, kq = lane >> 4;

    #pragma unroll
    for (int i = 0; i < 4; i++) {
        int c = t + i * 256;
        int n = c / 16, k8 = c % 16;
        *(u16x8*)&sWu[n * NSA + k8 * 8] = *(const u16x8*)&Wut[c * 8];
    }
    __syncthreads();

    int arow = n0 + w * 16 + col;
    if (arow >= N_NODES) arow = N_NODES - 1;                 // clamp (outputs guarded)
    const u16x8* pxr = (const u16x8*)(xb  + (size_t)arow * 64);
    const u16x8* par = (const u16x8*)(agg + (size_t)arow * 64);

    f32x4 acc[4] = {{0,0,0,0},{0,0,0,0},{0,0,0,0},{0,0,0,0}};
    #pragma unroll
    for (int ks = 0; ks < 4; ks++) {
        u16x8 av = (ks < 2) ? pxr[ks * 4 + kq] : par[(ks - 2) * 4 + kq];
        int ko = ks * 32 + kq * 8;
        #pragma unroll
        for (int ct = 0; ct < 4; ct++) {
            bf16x8 b = lds_frag(&sWu[(ct * 16 + col) * NSA + ko]);
            acc[ct] = MFMA_BF16(BC(av), b, acc[ct], 0, 0, 0);
        }
    }
    #pragma unroll
    for (int ct = 0; ct < 4; ct++) {
        float bb = bu[ct * 16 + col];
        #pragma unroll
        for (int r = 0; r < 4; r++) {
            int row = w * 16 + kq * 4 + r;
            int n = n0 + row;
            if (n < N_NODES) {
                int c2 = ct * 16 + col;
                float xa = x[(size_t)n * 64 + c2];          // exact fp32 residual
                out[(size_t)n * 64 + c2] = xa + fmaxf(acc[ct][r] + bb, 0.0f);
            }
        }
    }
}

extern "C" void kernel_launch(void* const* d_in, const int* in_sizes, int n_in,
                              void* d_out, int out_size, void* d_ws, size_t ws_size,
                              hipStream_t stream) {
    const float* x  = (const float*)d_in[0];
    const int*   ei = (const int*)  d_in[1];
    const float* ea = (const float*)d_in[2];
    const float* W1 = (const float*)d_in[3];
    const float* b1 = (const float*)d_in[4];
    const float* W2 = (const float*)d_in[5];
    const float* b2 = (const float*)d_in[6];
    const float* Wu = (const float*)d_in[7];
    const float* bu = (const float*)d_in[8];
    float* out = (float*)d_out;

    // workspace (~41 MB)
    unsigned short* agg = (unsigned short*)d_ws;                 // [N][64] bf16
    int* deg  = (int*)(agg + (size_t)N_NODES * HIDDEN);          // [N]
    int* ofs  = deg + N_NODES;                                   // [N+2]
    int* cur  = ofs + (N_NODES + 2);                             // [N]
    int* bsum = cur + N_NODES;                                   // [512]
    long long* elist = (long long*)(bsum + 512);                 // [E+16]
    unsigned short* W1t = (unsigned short*)(elist + N_EDGES + 16); // [64][160]
    unsigned short* W2t = W1t + 64 * 160;                        // [64][64]
    unsigned short* Wut = W2t + 64 * 64;                         // [64][128]
    unsigned short* xb  = Wut + 64 * 128;                        // [N][64] bf16

    // zero agg (deg==0 nodes keep 0) + deg histogram, one contiguous memset
    hipMemsetAsync(d_ws, 0,
                   (size_t)N_NODES * HIDDEN * sizeof(unsigned short)
                   + (size_t)N_NODES * sizeof(int), stream);

    prep_kernel<<<512, 256, 0, stream>>>(W1, b1, W2, Wu, x, ei, W1t, W2t, Wut, xb, deg);
    scan1_kernel<<<NB1, 256, 0, stream>>>(deg, ofs, bsum);
    scan2_kernel<<<1, 512, 0, stream>>>(bsum);
    scan3_kernel<<<NB1, 256, 0, stream>>>(ofs, bsum, cur);
    fill_kernel<<<1024, 256, 0, stream>>>(ei, cur, elist);
    agg_kernel<<<AGG_BLOCKS, 256, 0, stream>>>(xb, ea, elist, ofs,
                                               W1t, W2t, b2, agg);
    node_kernel<<<(N_NODES + 63) / 64, 256, 0, stream>>>(x, xb, agg, Wut, bu, out);
}